// Round 6
// baseline (334.580 us; speedup 1.0000x reference)
//
#include <hip/hip_runtime.h>

#define N_TOK 21952          // 28*28*28
#define NR    343            // 7*7*7
#define ATT_SCALE 0.17677669529663687f   // 32^-0.5

typedef unsigned short u16;
typedef short  v8s __attribute__((ext_vector_type(8)));
typedef float  v4f __attribute__((ext_vector_type(4)));

__device__ __forceinline__ float bf2f(unsigned u) {
    return __builtin_bit_cast(float, u << 16);
}
__device__ __forceinline__ u16 f2bf(float f) {
    unsigned u = __builtin_bit_cast(unsigned, f);
    u += 0x7fffu + ((u >> 16) & 1u);
    return (u16)(u >> 16);
}
__device__ __forceinline__ unsigned bfadd2(unsigned a, unsigned b) {
    float lo = bf2f(a & 0xffffu) + bf2f(b & 0xffffu);
    float hi = bf2f(a >> 16)     + bf2f(b >> 16);
    return (unsigned)f2bf(lo) | ((unsigned)f2bf(hi) << 16);
}

// ---------------------------------------------------------------------------
// Weight conversion fp32->bf16.
// wb_comb[768,256] = [lepe_w ; q1_w*s ; q2_w*s ; kv2_w], plus wb_k1, wb_p,
// and bias_all[768] = [lepe_b ; 0...].
// ---------------------------------------------------------------------------
#define WSEG0 16384   // lepe  (65536/4)
#define WSEG1 24576   // +q1   (32768/4)
#define WSEG2 32768   // +q2
#define WSEG3 49152   // +kv2  (65536/4)
#define WSEG4 65536   // +k1
#define WSEG5 81920   // +proj
#define WSEG6 82112   // +bias (768/4)

__global__ __launch_bounds__(256) void convert_w_kernel(
    const float* __restrict__ wl,  const float* __restrict__ wq1,
    const float* __restrict__ wq2, const float* __restrict__ wk2,
    const float* __restrict__ wk1, const float* __restrict__ wp,
    const float* __restrict__ lepe_b,
    u16* wb_comb, u16* wb_k1, u16* wb_p, float* bias_all)
{
    int gid = blockIdx.x * 256 + threadIdx.x;
    if (gid >= WSEG6) return;
    if (gid >= WSEG5) {                      // bias_all
        int b = gid - WSEG5;
        float4 v;
        int i = b * 4;
        v.x = (i + 0 < 256) ? lepe_b[i + 0] : 0.f;
        v.y = (i + 1 < 256) ? lepe_b[i + 1] : 0.f;
        v.z = (i + 2 < 256) ? lepe_b[i + 2] : 0.f;
        v.w = (i + 3 < 256) ? lepe_b[i + 3] : 0.f;
        *(float4*)(bias_all + i) = v;
        return;
    }
    const float* s; u16* d; int l; float sc = 1.f;
    if      (gid < WSEG0) { s = wl;  d = wb_comb;           l = gid; }
    else if (gid < WSEG1) { s = wq1; d = wb_comb + 65536;   l = gid - WSEG0; sc = ATT_SCALE; }
    else if (gid < WSEG2) { s = wq2; d = wb_comb + 98304;   l = gid - WSEG1; sc = ATT_SCALE; }
    else if (gid < WSEG3) { s = wk2; d = wb_comb + 131072;  l = gid - WSEG2; }
    else if (gid < WSEG4) { s = wk1; d = wb_k1;             l = gid - WSEG3; }
    else                  { s = wp;  d = wb_p;              l = gid - WSEG4; }
    float4 v = *(const float4*)(s + (size_t)l * 4);
    *(ushort4*)(d + (size_t)l * 4) =
        make_ushort4(f2bf(v.x * sc), f2bf(v.y * sc), f2bf(v.z * sc), f2bf(v.w * sc));
}

// ---------------------------------------------------------------------------
// sr_w [co][ci][tap] fp32 -> wsr_t [tap][co][ci] bf16.
// ---------------------------------------------------------------------------
__global__ __launch_bounds__(256) void convert_sr_kernel(
    const float* __restrict__ wsr, u16* __restrict__ wt)
{
    int u  = blockIdx.x * 256 + threadIdx.x;   // 65536 = 256 co x 256 ci
    int co = u >> 8, ci = u & 255;
    const float* src = wsr + (size_t)co * 16384 + ci * 64;
#pragma unroll
    for (int t4 = 0; t4 < 16; t4++) {
        float4 v = *(const float4*)(src + t4 * 4);
        int t = t4 * 4;
        wt[(size_t)(t + 0) * 65536 + co * 256 + ci] = f2bf(v.x);
        wt[(size_t)(t + 1) * 65536 + co * 256 + ci] = f2bf(v.y);
        wt[(size_t)(t + 2) * 65536 + co * 256 + ci] = f2bf(v.z);
        wt[(size_t)(t + 3) * 65536 + co * 256 + ci] = f2bf(v.w);
    }
}

// ---------------------------------------------------------------------------
// bf16 MFMA GEMM, software-pipelined (reg-prefetch of next K-tile):
// out[M,ldout] = (A [+ A2]) @ W^T [+ bias].  128x128 tile, BK=32, 4 waves.
// a_fp32: A is fp32, converted during LDS staging.
// mode: 0 = bf16 out (+bias), 1 = fp32 out (+bias)
// ---------------------------------------------------------------------------
#define LDA 40   // padded LDS row stride (bf16 elems)

__global__ __launch_bounds__(256) void gemm_bf16(
    const void* __restrict__ A, const u16* __restrict__ A2,
    const u16* __restrict__ W, const float* __restrict__ bias,
    void* __restrict__ outp, int M, int K, int ldout, int a_fp32, int mode)
{
    __shared__ u16 Asm[128 * LDA];
    __shared__ u16 Bsm[128 * LDA];
    const int tid = threadIdx.x;
    const int m0 = blockIdx.x * 128;
    const int n0 = blockIdx.y * 128;
    const int wave = tid >> 6, lane = tid & 63;
    const int wm = (wave & 1) * 64, wn = (wave >> 1) * 64;
    const int fr = lane & 15, fq = lane >> 4;

    v4f acc[4][4];
#pragma unroll
    for (int i = 0; i < 4; i++)
#pragma unroll
        for (int j = 0; j < 4; j++) acc[i][j] = (v4f){0.f, 0.f, 0.f, 0.f};

    float4 pa0[2], pa1[2];   // fp32-A prefetch regs
    uint4  pav[2];           // bf16-A prefetch regs
    uint4  pwv[2];           // W prefetch regs

    auto load_tile = [&](int kk) {
#pragma unroll
        for (int i = 0; i < 2; i++) {
            int u = tid + i * 256;           // 0..511
            int r = u >> 2, kc = (u & 3) * 8;
            int m = m0 + r;
            if (a_fp32) {
                float4 z = make_float4(0.f, 0.f, 0.f, 0.f);
                pa0[i] = z; pa1[i] = z;
                if (m < M) {
                    const float* Af = (const float*)A + (size_t)m * K + kk + kc;
                    pa0[i] = *(const float4*)Af;
                    pa1[i] = *(const float4*)(Af + 4);
                }
            } else {
                uint4 av = make_uint4(0, 0, 0, 0);
                if (m < M) {
                    av = *(const uint4*)((const u16*)A + (size_t)m * K + kk + kc);
                    if (A2) {
                        uint4 bv = *(const uint4*)(A2 + (size_t)m * K + kk + kc);
                        av.x = bfadd2(av.x, bv.x); av.y = bfadd2(av.y, bv.y);
                        av.z = bfadd2(av.z, bv.z); av.w = bfadd2(av.w, bv.w);
                    }
                }
                pav[i] = av;
            }
            pwv[i] = *(const uint4*)(W + (size_t)(n0 + r) * K + kk + kc);
        }
    };
    auto write_tile = [&]() {
#pragma unroll
        for (int i = 0; i < 2; i++) {
            int u = tid + i * 256;
            int r = u >> 2, kc = (u & 3) * 8;
            uint4 av;
            if (a_fp32) {
                av.x = (unsigned)f2bf(pa0[i].x) | ((unsigned)f2bf(pa0[i].y) << 16);
                av.y = (unsigned)f2bf(pa0[i].z) | ((unsigned)f2bf(pa0[i].w) << 16);
                av.z = (unsigned)f2bf(pa1[i].x) | ((unsigned)f2bf(pa1[i].y) << 16);
                av.w = (unsigned)f2bf(pa1[i].z) | ((unsigned)f2bf(pa1[i].w) << 16);
            } else {
                av = pav[i];
            }
            *(uint4*)(Asm + r * LDA + kc) = av;
            *(uint4*)(Bsm + r * LDA + kc) = pwv[i];
        }
    };

    load_tile(0);
    for (int kk = 0; kk < K; kk += 32) {
        write_tile();
        __syncthreads();
        if (kk + 32 < K) load_tile(kk + 32);   // overlap with MFMA below

        v8s af[4], bfr[4];
#pragma unroll
        for (int i = 0; i < 4; i++)
            af[i] = *(const v8s*)(Asm + (wm + i * 16 + fr) * LDA + fq * 8);
#pragma unroll
        for (int j = 0; j < 4; j++)
            bfr[j] = *(const v8s*)(Bsm + (wn + j * 16 + fr) * LDA + fq * 8);
#pragma unroll
        for (int i = 0; i < 4; i++)
#pragma unroll
            for (int j = 0; j < 4; j++)
                acc[i][j] = __builtin_amdgcn_mfma_f32_16x16x32_bf16(
                    af[i], bfr[j], acc[i][j], 0, 0, 0);
        __syncthreads();
    }

    float* outf = (float*)outp;
    u16*   outb = (u16*)outp;
#pragma unroll
    for (int i = 0; i < 4; i++) {
#pragma unroll
        for (int j = 0; j < 4; j++) {
            int col = n0 + wn + j * 16 + fr;
#pragma unroll
            for (int r = 0; r < 4; r++) {
                int row = m0 + wm + i * 16 + fq * 4 + r;
                if (row >= M) continue;
                float v = acc[i][j][r];
                if (bias) v += bias[col];
                if (mode == 0) outb[(size_t)row * ldout + col] = f2bf(v);
                else           outf[(size_t)row * ldout + col] = v;
            }
        }
    }
}

// ---------------------------------------------------------------------------
// SR conv as tap-split GEMM, software-pipelined like gemm_bf16.
// partials[z][p][co] = sum over taps {2z,2z+1} of x_rows(p,tap) @ wsr_t[tap]^T
// Grid (3, 2, 32).
// ---------------------------------------------------------------------------
__global__ __launch_bounds__(256) void sr_gemm(
    const float* __restrict__ x, const u16* __restrict__ Wt,
    float* __restrict__ partials)
{
    __shared__ u16 Asm[128 * LDA];
    __shared__ u16 Bsm[128 * LDA];
    const int tid = threadIdx.x;
    const int m0 = blockIdx.x * 128;   // p tile
    const int n0 = blockIdx.y * 128;   // co tile
    const int z  = blockIdx.z;         // taps 2z, 2z+1
    const int wave = tid >> 6, lane = tid & 63;
    const int wm = (wave & 1) * 64, wn = (wave >> 1) * 64;
    const int fr = lane & 15, fq = lane >> 4;

    v4f acc[4][4];
#pragma unroll
    for (int i = 0; i < 4; i++)
#pragma unroll
        for (int j = 0; j < 4; j++) acc[i][j] = (v4f){0.f, 0.f, 0.f, 0.f};

    float4 pa0[2], pa1[2];
    uint4  pwv[2];

    auto load_tile = [&](int it) {
        int tap = z * 2 + (it >> 3);
        int ci0 = (it & 7) * 32;
        int kz = tap >> 4, ky = (tap >> 2) & 3, kx = tap & 3;
#pragma unroll
        for (int i = 0; i < 2; i++) {
            int u = tid + i * 256;
            int r = u >> 2, seg = (u & 3) * 8;
            float4 zf = make_float4(0.f, 0.f, 0.f, 0.f);
            pa0[i] = zf; pa1[i] = zf;
            int p = m0 + r;
            if (p < NR) {
                int pz = p / 49, pr = p % 49, py = pr / 7, px = pr % 7;
                int n = (pz * 4 + kz) * 784 + (py * 4 + ky) * 28 + (px * 4 + kx);
                const float* src = x + (size_t)n * 256 + ci0 + seg;
                pa0[i] = *(const float4*)src;
                pa1[i] = *(const float4*)(src + 4);
            }
            pwv[i] = *(const uint4*)(Wt + (size_t)tap * 65536 +
                                     (size_t)(n0 + r) * 256 + ci0 + seg);
        }
    };
    auto write_tile = [&]() {
#pragma unroll
        for (int i = 0; i < 2; i++) {
            int u = tid + i * 256;
            int r = u >> 2, seg = (u & 3) * 8;
            uint4 av;
            av.x = (unsigned)f2bf(pa0[i].x) | ((unsigned)f2bf(pa0[i].y) << 16);
            av.y = (unsigned)f2bf(pa0[i].z) | ((unsigned)f2bf(pa0[i].w) << 16);
            av.z = (unsigned)f2bf(pa1[i].x) | ((unsigned)f2bf(pa1[i].y) << 16);
            av.w = (unsigned)f2bf(pa1[i].z) | ((unsigned)f2bf(pa1[i].w) << 16);
            *(uint4*)(Asm + r * LDA + seg) = av;
            *(uint4*)(Bsm + r * LDA + seg) = pwv[i];
        }
    };

    load_tile(0);
    for (int it = 0; it < 16; it++) {
        write_tile();
        __syncthreads();
        if (it + 1 < 16) load_tile(it + 1);

        v8s af[4], bfr[4];
#pragma unroll
        for (int i = 0; i < 4; i++)
            af[i] = *(const v8s*)(Asm + (wm + i * 16 + fr) * LDA + fq * 8);
#pragma unroll
        for (int j = 0; j < 4; j++)
            bfr[j] = *(const v8s*)(Bsm + (wn + j * 16 + fr) * LDA + fq * 8);
#pragma unroll
        for (int i = 0; i < 4; i++)
#pragma unroll
            for (int j = 0; j < 4; j++)
                acc[i][j] = __builtin_amdgcn_mfma_f32_16x16x32_bf16(
                    af[i], bfr[j], acc[i][j], 0, 0, 0);
        __syncthreads();
    }

    float* dst = partials + (size_t)z * (NR * 256);
#pragma unroll
    for (int i = 0; i < 4; i++) {
#pragma unroll
        for (int j = 0; j < 4; j++) {
            int col = n0 + wn + j * 16 + fr;
#pragma unroll
            for (int r = 0; r < 4; r++) {
                int row = m0 + wm + i * 16 + fq * 4 + r;
                if (row < NR) dst[(size_t)row * 256 + col] = acc[i][j][r];
            }
        }
    }
}

// ---------------------------------------------------------------------------
// Reduce 32 partials + sr bias, LayerNorm (C=256) + exact GELU -> bf16.
// ---------------------------------------------------------------------------
__global__ __launch_bounds__(256) void ln_gelu_kernel(
    const float* __restrict__ partials, const float* __restrict__ srb,
    const float* __restrict__ g, const float* __restrict__ b,
    u16* __restrict__ out)
{
    int row = blockIdx.x, c = threadIdx.x;
    float v = srb[c];
#pragma unroll
    for (int s = 0; s < 32; s++)
        v += partials[(size_t)s * (NR * 256) + row * 256 + c];
    float s1 = v, s2 = v * v;
#pragma unroll
    for (int off = 1; off < 64; off <<= 1) {
        s1 += __shfl_xor(s1, off);
        s2 += __shfl_xor(s2, off);
    }
    __shared__ float ws[4], ws2[4];
    int wave = c >> 6, lane = c & 63;
    if (lane == 0) { ws[wave] = s1; ws2[wave] = s2; }
    __syncthreads();
    float mean = (ws[0] + ws[1] + ws[2] + ws[3]) * (1.f / 256.f);
    float m2   = (ws2[0] + ws2[1] + ws2[2] + ws2[3]) * (1.f / 256.f);
    float var  = m2 - mean * mean;
    float xn = (v - mean) * rsqrtf(var + 1e-5f) * g[c] + b[c];
    out[row * 256 + c] = f2bf(0.5f * xn * (1.f + erff(xn * 0.70710678118654752f)));
}

// ---------------------------------------------------------------------------
// Depthwise 3x3x3 SAME conv, LDS-tiled.  y = xall cols 0..255 (row stride 768).
// ---------------------------------------------------------------------------
__global__ __launch_bounds__(256) void dwconv_kernel(
    const u16* __restrict__ xall, const float* __restrict__ w,
    const float* __restrict__ bias, u16* __restrict__ out)
{
    __shared__ float sm[216 * 64];
    __shared__ float sw[64 * 27];
    const int tid = threadIdx.x;
    const int t  = blockIdx.x;
    const int g  = blockIdx.y;
    const int tz = t / 49, tr = t % 49, ty = tr / 7, tx = tr % 7;

    for (int u = tid; u < 64 * 27; u += 256) sw[u] = w[g * 64 * 27 + u];

    for (int u = tid; u < 216 * 8; u += 256) {
        int r = u >> 3, c8 = (u & 7) * 8;
        int vz = tz * 4 - 1 + r / 36;
        int rem = r % 36;
        int vy = ty * 4 - 1 + rem / 6;
        int vx = tx * 4 - 1 + rem % 6;
        float f[8];
        if ((unsigned)vz < 28u && (unsigned)vy < 28u && (unsigned)vx < 28u) {
            int n = vz * 784 + vy * 28 + vx;
            uint4 raw = *(const uint4*)(xall + (size_t)n * 768 + g * 64 + c8);
            f[0] = bf2f(raw.x & 0xffffu); f[1] = bf2f(raw.x >> 16);
            f[2] = bf2f(raw.y & 0xffffu); f[3] = bf2f(raw.y >> 16);
            f[4] = bf2f(raw.z & 0xffffu); f[5] = bf2f(raw.z >> 16);
            f[6] = bf2f(raw.w & 0xffffu); f[7] = bf2f(raw.w >> 16);
        } else {
#pragma unroll
            for (int i = 0; i < 8; i++) f[i] = 0.f;
        }
        float* dst = &sm[r * 64 + c8];
        *(float4*)dst       = make_float4(f[0], f[1], f[2], f[3]);
        *(float4*)(dst + 4) = make_float4(f[4], f[5], f[6], f[7]);
    }
    __syncthreads();

    const int c  = tid & 63;
    const int ch = g * 64 + c;
    float wreg[27];
#pragma unroll
    for (int j = 0; j < 27; j++) wreg[j] = sw[c * 27 + j];
    const float bc = bias[ch];

    const int vbase = (tid >> 6) * 16;
    for (int v = vbase; v < vbase + 16; v++) {
        int vz = v >> 4, vy = (v >> 2) & 3, vx = v & 3;
        float a = bc;
#pragma unroll
        for (int dz = 0; dz < 3; dz++)
#pragma unroll
            for (int dy = 0; dy < 3; dy++)
#pragma unroll
                for (int dx = 0; dx < 3; dx++)
                    a = fmaf(sm[((vz + dz) * 36 + (vy + dy) * 6 + (vx + dx)) * 64 + c],
                             wreg[dz * 9 + dy * 3 + dx], a);
        int n = (tz * 4 + vz) * 784 + (ty * 4 + vy) * 28 + (tx * 4 + vx);
        out[(size_t)n * 256 + ch] = f2bf(a);
    }
}

// ===========================================================================
// MFMA attention.  Grid z splits the 22 m-tiles in half (z*11 .. z*11+10)
// for 2 blocks/CU occupancy (LDS-capped).  Fragment conventions as gemm_bf16.
// ===========================================================================
#define KP  40    // K LDS row stride (bf16)
#define VTP 360   // V^T LDS row stride (bf16)
#define PP  40    // P LDS row stride (bf16)

// Branch 1: q = xall cols 256..383 (stride 768); kv1: [343,256].
__global__ __launch_bounds__(256) void attn1_kernel(
    const u16* __restrict__ xall, const u16* __restrict__ kv1,
    u16* __restrict__ o)
{
    __shared__ u16 Ks[352 * KP];
    __shared__ u16 VTs[32 * VTP];
    __shared__ u16 Ps[4 * 16 * PP];
    const int tid = threadIdx.x;
    const int h = blockIdx.y;
    const int qbase = blockIdx.x * 352;
    const int mt0 = blockIdx.z * 11;
    const int wave = tid >> 6, lane = tid & 63;
    const int fr = lane & 15, fq = lane >> 4;

    for (int u = tid; u < 352 * 4; u += 256) {
        int r = u >> 2, seg = u & 3;
        uint4 kq = make_uint4(0, 0, 0, 0), vq = make_uint4(0, 0, 0, 0);
        if (r < NR) {
            kq = *(const uint4*)(kv1 + (size_t)r * 256 + h * 32 + seg * 8);
            vq = *(const uint4*)(kv1 + (size_t)r * 256 + 128 + h * 32 + seg * 8);
        }
        *(uint4*)(Ks + r * KP + seg * 8) = kq;
        int d0 = seg * 8;
        VTs[(d0 + 0) * VTP + r] = (u16)(vq.x & 0xffffu);
        VTs[(d0 + 1) * VTP + r] = (u16)(vq.x >> 16);
        VTs[(d0 + 2) * VTP + r] = (u16)(vq.y & 0xffffu);
        VTs[(d0 + 3) * VTP + r] = (u16)(vq.y >> 16);
        VTs[(d0 + 4) * VTP + r] = (u16)(vq.z & 0xffffu);
        VTs[(d0 + 5) * VTP + r] = (u16)(vq.z >> 16);
        VTs[(d0 + 6) * VTP + r] = (u16)(vq.w & 0xffffu);
        VTs[(d0 + 7) * VTP + r] = (u16)(vq.w >> 16);
    }
    __syncthreads();

    u16* Pw = Ps + wave * 16 * PP;
    for (int mt = mt0 + wave; mt < mt0 + 11; mt += 4) {
        int qrow = qbase + mt * 16 + fr;
        v8s aq = {0, 0, 0, 0, 0, 0, 0, 0};
        if (qrow < N_TOK)
            aq = *(const v8s*)(xall + (size_t)qrow * 768 + 256 + h * 32 + fq * 8);

        v4f s[22];
#pragma unroll
        for (int t = 0; t < 22; t++) {
            v8s bk = *(const v8s*)(Ks + (t * 16 + fr) * KP + fq * 8);
            s[t] = __builtin_amdgcn_mfma_f32_16x16x32_bf16(
                aq, bk, (v4f){0.f, 0.f, 0.f, 0.f}, 0, 0, 0);
        }
        if (fr >= 7) {
#pragma unroll
            for (int r = 0; r < 4; r++) s[21][r] = -1e30f;
        }

        float inv_l[4];
#pragma unroll
        for (int r = 0; r < 4; r++) {
            float m = s[0][r];
#pragma unroll
            for (int t = 1; t < 22; t++) m = fmaxf(m, s[t][r]);
#pragma unroll
            for (int off = 1; off < 16; off <<= 1) m = fmaxf(m, __shfl_xor(m, off));
            float l = 0.f;
#pragma unroll
            for (int t = 0; t < 22; t++) {
                v4f sv = s[t];
                float p = __expf(sv[r] - m);
                sv[r] = p; s[t] = sv;
                l += p;
            }
#pragma unroll
            for (int off = 1; off < 16; off <<= 1) l += __shfl_xor(l, off);
            inv_l[r] = 1.f / l;
        }

        v4f o0 = {0.f, 0.f, 0.f, 0.f}, o1 = {0.f, 0.f, 0.f, 0.f};
#pragma unroll
        for (int kt = 0; kt < 11; kt++) {
#pragma unroll
            for (int tt = 0; tt < 2; tt++) {
                int t = kt * 2 + tt;
#pragma unroll
                for (int r = 0; r < 4; r++)
                    Pw[(fq * 4 + r) * PP + tt * 16 + fr] = f2bf(s[t][r]);
            }
            __asm__ volatile("s_waitcnt lgkmcnt(0)" ::: "memory");
            v8s ap  = *(const v8s*)(Pw + fr * PP + fq * 8);
            v8s bv0 = *(const v8s*)(VTs + fr * VTP + kt * 32 + fq * 8);
            v8s bv1 = *(const v8s*)(VTs + (16 + fr) * VTP + kt * 32 + fq * 8);
            o0 = __builtin_amdgcn_mfma_f32_16x16x32_bf16(ap, bv0, o0, 0, 0, 0);
            o1 = __builtin_amdgcn_mfma_f32_16x16x32_bf16(ap, bv1, o1, 0, 0, 0);
        }

#pragma unroll
        for (int r = 0; r < 4; r++) {
            int n = qbase + mt * 16 + fq * 4 + r;
            if (n < N_TOK) {
                u16* op = o + (size_t)n * 256 + h * 32;
                op[fr]      = f2bf(o0[r] * inv_l[r]);
                op[16 + fr] = f2bf(o1[r] * inv_l[r]);
            }
        }
    }
}

// Branch 2: q = xall cols 384..511; kv2 = xall cols 512..767 (stride 768).
__global__ __launch_bounds__(256) void attn2_kernel(
    const u16* __restrict__ xall, u16* __restrict__ o)
{
    __shared__ u16 Ks[352 * KP];
    __shared__ u16 VTs[32 * VTP];
    __shared__ u16 Ps[4 * 16 * PP];
    const int tid = threadIdx.x;
    const int h  = blockIdx.y;
    const int wi = blockIdx.x;
    const int zb = (wi >> 4) & 3, yb = (wi >> 2) & 3, xb = wi & 3;
    const int mt0 = blockIdx.z * 11;
    const int wave = tid >> 6, lane = tid & 63;
    const int fr = lane & 15, fq = lane >> 4;

    for (int u = tid; u < 352 * 4; u += 256) {
        int r = u >> 2, seg = u & 3;
        uint4 kq = make_uint4(0, 0, 0, 0), vq = make_uint4(0, 0, 0, 0);
        if (r < NR) {
            int mz = r / 49, mr = r % 49, my = mr / 7, mx = mr % 7;
            int nk = (zb * 7 + mz) * 784 + (yb * 7 + my) * 28 + (xb * 7 + mx);
            const u16* base = xall + (size_t)nk * 768 + 512;
            kq = *(const uint4*)(base + h * 32 + seg * 8);
            vq = *(const uint4*)(base + 128 + h * 32 + seg * 8);
        }
        *(uint4*)(Ks + r * KP + seg * 8) = kq;
        int d0 = seg * 8;
        VTs[(d0 + 0) * VTP + r] = (u16)(vq.x & 0xffffu);
        VTs[(d0 + 1) * VTP + r] = (u16)(vq.x >> 16);
        VTs[(d0 + 2) * VTP + r] = (u16)(vq.y & 0xffffu);
        VTs[(d0 + 3) * VTP + r] = (u16)(vq.y >> 16);
        VTs[(d0 + 4) * VTP + r] = (u16)(vq.z & 0xffffu);
        VTs[(d0 + 5) * VTP + r] = (u16)(vq.z >> 16);
        VTs[(d0 + 6) * VTP + r] = (u16)(vq.w & 0xffffu);
        VTs[(d0 + 7) * VTP + r] = (u16)(vq.w >> 16);
    }
    __syncthreads();

    u16* Pw = Ps + wave * 16 * PP;
    for (int mt = mt0 + wave; mt < mt0 + 11; mt += 4) {
        int tw = mt * 16 + fr;
        v8s aq = {0, 0, 0, 0, 0, 0, 0, 0};
        if (tw < NR) {
            int wz = tw / 49, tr2 = tw % 49, wy = tr2 / 7, wx = tr2 % 7;
            int nq = (zb * 7 + wz) * 784 + (yb * 7 + wy) * 28 + (xb * 7 + wx);
            aq = *(const v8s*)(xall + (size_t)nq * 768 + 384 + h * 32 + fq * 8);
        }

        v4f s[22];
#pragma unroll
        for (int t = 0; t < 22; t++) {
            v8s bk = *(const v8s*)(Ks + (t * 16 + fr) * KP + fq * 8);
            s[t] = __builtin_amdgcn_mfma_f32_16x16x32_bf16(
                aq, bk, (v4f){0.f, 0.f, 0.f, 0.f}, 0, 0, 0);
        }
        if (fr >= 7) {
#pragma unroll
            for (int r = 0; r < 4; r++) s[21][r] = -1e30f;
        }

        float inv_l[4];
#pragma unroll
        for (int r = 0; r < 4; r++) {
            float m = s[0][r];
#pragma unroll
            for (int t = 1; t < 22; t++) m = fmaxf(m, s[t][r]);
#pragma unroll
            for (int off = 1; off < 16; off <<= 1) m = fmaxf(m, __shfl_xor(m, off));
            float l = 0.f;
#pragma unroll
            for (int t = 0; t < 22; t++) {
                v4f sv = s[t];
                float p = __expf(sv[r] - m);
                sv[r] = p; s[t] = sv;
                l += p;
            }
#pragma unroll
            for (int off = 1; off < 16; off <<= 1) l += __shfl_xor(l, off);
            inv_l[r] = 1.f / l;
        }

        v4f o0 = {0.f, 0.f, 0.f, 0.f}, o1 = {0.f, 0.f, 0.f, 0.f};
#pragma unroll
        for (int kt = 0; kt < 11; kt++) {
#pragma unroll
            for (int tt = 0; tt < 2; tt++) {
                int t = kt * 2 + tt;
#pragma unroll
                for (int r = 0; r < 4; r++)
                    Pw[(fq * 4 + r) * PP + tt * 16 + fr] = f2bf(s[t][r]);
            }
            __asm__ volatile("s_waitcnt lgkmcnt(0)" ::: "memory");
            v8s ap  = *(const v8s*)(Pw + fr * PP + fq * 8);
            v8s bv0 = *(const v8s*)(VTs + fr * VTP + kt * 32 + fq * 8);
            v8s bv1 = *(const v8s*)(VTs + (16 + fr) * VTP + kt * 32 + fq * 8);
            o0 = __builtin_amdgcn_mfma_f32_16x16x32_bf16(ap, bv0, o0, 0, 0, 0);
            o1 = __builtin_amdgcn_mfma_f32_16x16x32_bf16(ap, bv1, o1, 0, 0, 0);
        }

#pragma unroll
        for (int r = 0; r < 4; r++) {
            int ts = mt * 16 + fq * 4 + r;
            if (ts < NR) {
                int wz = ts / 49, tr2 = ts % 49, wy = tr2 / 7, wx = tr2 % 7;
                int nq = (zb * 7 + wz) * 784 + (yb * 7 + wy) * 28 + (xb * 7 + wx);
                u16* op = o + (size_t)nq * 256 + 128 + h * 32;
                op[fr]      = f2bf(o0[r] * inv_l[r]);
                op[16 + fr] = f2bf(o1[r] * inv_l[r]);
            }
        }
    }
}

// ---------------------------------------------------------------------------
extern "C" void kernel_launch(void* const* d_in, const int* in_sizes, int n_in,
                              void* d_out, int out_size, void* d_ws, size_t ws_size,
                              hipStream_t stream)
{
    const float* x       = (const float*)d_in[0];
    const float* lepe_w  = (const float*)d_in[4];
    const float* lepe_b  = (const float*)d_in[5];
    const float* lconv_w = (const float*)d_in[6];
    const float* lconv_b = (const float*)d_in[7];
    const float* sr_w    = (const float*)d_in[8];
    const float* sr_b    = (const float*)d_in[9];
    const float* norm_g  = (const float*)d_in[10];
    const float* norm_b  = (const float*)d_in[11];
    const float* q1_w    = (const float*)d_in[12];
    const float* kv1_w   = (const float*)d_in[13];
    const float* q2_w    = (const float*)d_in[14];
    const float* kv2_w   = (const float*)d_in[15];
    const float* proj_w  = (const float*)d_in[16];
    const float* proj_b  = (const float*)d_in[17];
    float* out = (float*)d_out;

    const size_t NC = (size_t)N_TOK * 256;

    float* partials = (float*)d_ws;                 // [32][343*256] fp32
    float* bias_all = partials + 32 * (NR * 256);   // [768]
    u16* xall   = (u16*)(bias_all + 768);           // [N,768]: y|q1|q2|kv2
    u16* lepeb  = xall + (size_t)N_TOK * 768;       // [N,256]
    u16* colb   = lepeb + NC;                       // o concat [N,256]
    u16* x1b    = colb + NC;                        // [343,256]
    u16* kv1b   = x1b + NR * 256;                   // [343,256]
    u16* wb_comb = kv1b + NR * 256;                 // [768,256]
    u16* wb_k1  = wb_comb + 196608;                 // [256,256]
    u16* wb_p   = wb_k1 + 65536;                    // [256,256]
    u16* wsr_t  = wb_p + 65536;                     // [64][256,256]
    size_t need = (size_t)(32 * NR * 256 + 768) * 4 +
                  ((size_t)N_TOK * 768 + 2 * NC + 2 * (size_t)NR * 256 +
                   196608 + 2 * 65536 + 4194304) * 2;
    if (ws_size < need) return;

    // 0a. weights -> bf16 (q pre-scaled), bias_all
    convert_w_kernel<<<dim3(321), 256, 0, stream>>>(
        lepe_w, q1_w, q2_w, kv2_w, kv1_w, proj_w, lepe_b,
        wb_comb, wb_k1, wb_p, bias_all);
    // 0b. sr_w -> [tap][co][ci] bf16
    convert_sr_kernel<<<dim3(256), 256, 0, stream>>>(sr_w, wsr_t);
    // 1. xall = x @ [lepe|q1|q2|kv2]^T + bias_all   (fp32 A, bf16 out)
    gemm_bf16<<<dim3(172, 6), 256, 0, stream>>>(x, nullptr, wb_comb, bias_all,
                                                xall, N_TOK, 256, 768, 1, 0);
    // 2. lepe = depthwise conv(y)
    dwconv_kernel<<<dim3(343, 4), 256, 0, stream>>>(xall, lconv_w, lconv_b, lepeb);
    // 3. SR conv: tap-split GEMM into partials
    sr_gemm<<<dim3(3, 2, 32), 256, 0, stream>>>(x, wsr_t, partials);
    // 4. x1 = gelu(layernorm(sum partials + sr_b))
    ln_gelu_kernel<<<dim3(NR), 256, 0, stream>>>(partials, sr_b, norm_g, norm_b, x1b);
    // 5. kv1 = x1 @ kv1_w^T
    gemm_bf16<<<dim3(3, 2), 256, 0, stream>>>(x1b, nullptr, wb_k1, nullptr,
                                              kv1b, NR, 256, 256, 0, 0);
    // 6. branch-1 MFMA attention -> o[:, :128]
    attn1_kernel<<<dim3(63, 4, 2), 256, 0, stream>>>(xall, kv1b, colb);
    // 7. branch-2 windowed MFMA attention -> o[:, 128:]
    attn2_kernel<<<dim3(64, 4, 2), 256, 0, stream>>>(xall, colb);
    // 8. out = (o + lepe) @ proj_w^T + proj_b  (fp32 out)
    gemm_bf16<<<dim3(172, 2), 256, 0, stream>>>(colb, lepeb, wb_p, proj_b,
                                                out, N_TOK, 256, 256, 0, 1);
}

// Round 8
// 293.436 us; speedup vs baseline: 1.1402x; 1.1402x over previous
//
#include <hip/hip_runtime.h>

#define N_TOK 21952          // 28*28*28
#define NR    343            // 7*7*7
#define ATT_SCALE 0.17677669529663687f   // 32^-0.5

typedef unsigned short u16;
typedef short  v8s __attribute__((ext_vector_type(8)));
typedef float  v4f __attribute__((ext_vector_type(4)));

__device__ __forceinline__ float bf2f(unsigned u) {
    return __builtin_bit_cast(float, u << 16);
}
__device__ __forceinline__ u16 f2bf(float f) {
    unsigned u = __builtin_bit_cast(unsigned, f);
    u += 0x7fffu + ((u >> 16) & 1u);
    return (u16)(u >> 16);
}
__device__ __forceinline__ unsigned bfadd2(unsigned a, unsigned b) {
    float lo = bf2f(a & 0xffffu) + bf2f(b & 0xffffu);
    float hi = bf2f(a >> 16)     + bf2f(b >> 16);
    return (unsigned)f2bf(lo) | ((unsigned)f2bf(hi) << 16);
}

// ---------------------------------------------------------------------------
// x fp32 -> bf16 (xb).  8 elems / thread, exact grid.
// ---------------------------------------------------------------------------
__global__ __launch_bounds__(256) void convert_x_kernel(
    const float* __restrict__ x, u16* __restrict__ xb)
{
    size_t i = ((size_t)blockIdx.x * 256 + threadIdx.x) * 8;   // exact: N*256
    float4 a0 = *(const float4*)(x + i);
    float4 a1 = *(const float4*)(x + i + 4);
    uint4 av;
    av.x = (unsigned)f2bf(a0.x) | ((unsigned)f2bf(a0.y) << 16);
    av.y = (unsigned)f2bf(a0.z) | ((unsigned)f2bf(a0.w) << 16);
    av.z = (unsigned)f2bf(a1.x) | ((unsigned)f2bf(a1.y) << 16);
    av.w = (unsigned)f2bf(a1.z) | ((unsigned)f2bf(a1.w) << 16);
    *(uint4*)(xb + i) = av;
}

// ---------------------------------------------------------------------------
// Weight conversion fp32->bf16.
// wb_comb[768,256] = [lepe_w ; q1_w*s ; q2_w*s ; kv2_w], plus wb_k1, wb_p,
// and bias_all[768] = [lepe_b ; 0...].
// ---------------------------------------------------------------------------
#define WSEG0 16384   // lepe  (65536/4)
#define WSEG1 24576   // +q1   (32768/4)
#define WSEG2 32768   // +q2
#define WSEG3 49152   // +kv2  (65536/4)
#define WSEG4 65536   // +k1
#define WSEG5 81920   // +proj
#define WSEG6 82112   // +bias (768/4)

__global__ __launch_bounds__(256) void convert_w_kernel(
    const float* __restrict__ wl,  const float* __restrict__ wq1,
    const float* __restrict__ wq2, const float* __restrict__ wk2,
    const float* __restrict__ wk1, const float* __restrict__ wp,
    const float* __restrict__ lepe_b,
    u16* wb_comb, u16* wb_k1, u16* wb_p, float* bias_all)
{
    int gid = blockIdx.x * 256 + threadIdx.x;
    if (gid >= WSEG6) return;
    if (gid >= WSEG5) {                      // bias_all
        int b = gid - WSEG5;
        float4 v;
        int i = b * 4;
        v.x = (i + 0 < 256) ? lepe_b[i + 0] : 0.f;
        v.y = (i + 1 < 256) ? lepe_b[i + 1] : 0.f;
        v.z = (i + 2 < 256) ? lepe_b[i + 2] : 0.f;
        v.w = (i + 3 < 256) ? lepe_b[i + 3] : 0.f;
        *(float4*)(bias_all + i) = v;
        return;
    }
    const float* s; u16* d; int l; float sc = 1.f;
    if      (gid < WSEG0) { s = wl;  d = wb_comb;           l = gid; }
    else if (gid < WSEG1) { s = wq1; d = wb_comb + 65536;   l = gid - WSEG0; sc = ATT_SCALE; }
    else if (gid < WSEG2) { s = wq2; d = wb_comb + 98304;   l = gid - WSEG1; sc = ATT_SCALE; }
    else if (gid < WSEG3) { s = wk2; d = wb_comb + 131072;  l = gid - WSEG2; }
    else if (gid < WSEG4) { s = wk1; d = wb_k1;             l = gid - WSEG3; }
    else                  { s = wp;  d = wb_p;              l = gid - WSEG4; }
    float4 v = *(const float4*)(s + (size_t)l * 4);
    *(ushort4*)(d + (size_t)l * 4) =
        make_ushort4(f2bf(v.x * sc), f2bf(v.y * sc), f2bf(v.z * sc), f2bf(v.w * sc));
}

// ---------------------------------------------------------------------------
// sr_w [co][ci][tap] fp32 -> wsr_t [tap][co][ci] bf16.
// ---------------------------------------------------------------------------
__global__ __launch_bounds__(256) void convert_sr_kernel(
    const float* __restrict__ wsr, u16* __restrict__ wt)
{
    int u  = blockIdx.x * 256 + threadIdx.x;   // 65536 = 256 co x 256 ci
    int co = u >> 8, ci = u & 255;
    const float* src = wsr + (size_t)co * 16384 + ci * 64;
#pragma unroll
    for (int t4 = 0; t4 < 16; t4++) {
        float4 v = *(const float4*)(src + t4 * 4);
        int t = t4 * 4;
        wt[(size_t)(t + 0) * 65536 + co * 256 + ci] = f2bf(v.x);
        wt[(size_t)(t + 1) * 65536 + co * 256 + ci] = f2bf(v.y);
        wt[(size_t)(t + 2) * 65536 + co * 256 + ci] = f2bf(v.z);
        wt[(size_t)(t + 3) * 65536 + co * 256 + ci] = f2bf(v.w);
    }
}

// ---------------------------------------------------------------------------
// bf16 MFMA GEMM (round-5 validated): out[M,ldout] = (A [+ A2]) @ W^T [+ bias]
// 128x128 tile, BK=32, 4 waves (2x2), 4x4 mfma 16x16x32 per wave.
// a_fp32: A is fp32, converted during staging.
// mode: 0 = bf16 out (+bias), 1 = fp32 out (+bias)
// ---------------------------------------------------------------------------
#define LDA 40   // padded LDS row stride (bf16 elems)

__global__ __launch_bounds__(256) void gemm_bf16(
    const void* __restrict__ A, const u16* __restrict__ A2,
    const u16* __restrict__ W, const float* __restrict__ bias,
    void* __restrict__ outp, int M, int K, int ldout, int a_fp32, int mode)
{
    __shared__ u16 Asm[128 * LDA];
    __shared__ u16 Bsm[128 * LDA];
    const int tid = threadIdx.x;
    const int m0 = blockIdx.x * 128;
    const int n0 = blockIdx.y * 128;
    const int wave = tid >> 6, lane = tid & 63;
    const int wm = (wave & 1) * 64, wn = (wave >> 1) * 64;
    const int fr = lane & 15, fq = lane >> 4;

    v4f acc[4][4];
#pragma unroll
    for (int i = 0; i < 4; i++)
#pragma unroll
        for (int j = 0; j < 4; j++) acc[i][j] = (v4f){0.f, 0.f, 0.f, 0.f};

    for (int kk = 0; kk < K; kk += 32) {
#pragma unroll
        for (int i = 0; i < 2; i++) {
            int u = tid + i * 256;           // 0..511
            int r = u >> 2, kc = (u & 3) * 8;
            uint4 av = make_uint4(0, 0, 0, 0);
            int m = m0 + r;
            if (m < M) {
                if (a_fp32) {
                    const float* Af = (const float*)A + (size_t)m * K + kk + kc;
                    float4 a0 = *(const float4*)Af;
                    float4 a1 = *(const float4*)(Af + 4);
                    av.x = (unsigned)f2bf(a0.x) | ((unsigned)f2bf(a0.y) << 16);
                    av.y = (unsigned)f2bf(a0.z) | ((unsigned)f2bf(a0.w) << 16);
                    av.z = (unsigned)f2bf(a1.x) | ((unsigned)f2bf(a1.y) << 16);
                    av.w = (unsigned)f2bf(a1.z) | ((unsigned)f2bf(a1.w) << 16);
                } else {
                    av = *(const uint4*)((const u16*)A + (size_t)m * K + kk + kc);
                    if (A2) {
                        uint4 bv = *(const uint4*)(A2 + (size_t)m * K + kk + kc);
                        av.x = bfadd2(av.x, bv.x); av.y = bfadd2(av.y, bv.y);
                        av.z = bfadd2(av.z, bv.z); av.w = bfadd2(av.w, bv.w);
                    }
                }
            }
            *(uint4*)(Asm + r * LDA + kc) = av;
            uint4 wv = *(const uint4*)(W + (size_t)(n0 + r) * K + kk + kc);
            *(uint4*)(Bsm + r * LDA + kc) = wv;
        }
        __syncthreads();

        v8s af[4], bfr[4];
#pragma unroll
        for (int i = 0; i < 4; i++)
            af[i] = *(const v8s*)(Asm + (wm + i * 16 + fr) * LDA + fq * 8);
#pragma unroll
        for (int j = 0; j < 4; j++)
            bfr[j] = *(const v8s*)(Bsm + (wn + j * 16 + fr) * LDA + fq * 8);
#pragma unroll
        for (int i = 0; i < 4; i++)
#pragma unroll
            for (int j = 0; j < 4; j++)
                acc[i][j] = __builtin_amdgcn_mfma_f32_16x16x32_bf16(
                    af[i], bfr[j], acc[i][j], 0, 0, 0);
        __syncthreads();
    }

    float* outf = (float*)outp;
    u16*   outb = (u16*)outp;
#pragma unroll
    for (int i = 0; i < 4; i++) {
#pragma unroll
        for (int j = 0; j < 4; j++) {
            int col = n0 + wn + j * 16 + fr;
#pragma unroll
            for (int r = 0; r < 4; r++) {
                int row = m0 + wm + i * 16 + fq * 4 + r;
                if (row >= M) continue;
                float v = acc[i][j][r];
                if (bias) v += bias[col];
                if (mode == 0) outb[(size_t)row * ldout + col] = f2bf(v);
                else           outf[(size_t)row * ldout + col] = v;
            }
        }
    }
}

// ---------------------------------------------------------------------------
// SR conv as tap-split GEMM (round-5 structure; A now staged from bf16 xb).
// partials[z][p][co] = sum over taps {2z,2z+1} of x_rows(p,tap) @ wsr_t[tap]^T
// Grid (3, 2, 32).
// ---------------------------------------------------------------------------
__global__ __launch_bounds__(256) void sr_gemm(
    const u16* __restrict__ xb, const u16* __restrict__ Wt,
    float* __restrict__ partials)
{
    __shared__ u16 Asm[128 * LDA];
    __shared__ u16 Bsm[128 * LDA];
    const int tid = threadIdx.x;
    const int m0 = blockIdx.x * 128;   // p tile
    const int n0 = blockIdx.y * 128;   // co tile
    const int z  = blockIdx.z;         // taps 2z, 2z+1
    const int wave = tid >> 6, lane = tid & 63;
    const int wm = (wave & 1) * 64, wn = (wave >> 1) * 64;
    const int fr = lane & 15, fq = lane >> 4;

    v4f acc[4][4];
#pragma unroll
    for (int i = 0; i < 4; i++)
#pragma unroll
        for (int j = 0; j < 4; j++) acc[i][j] = (v4f){0.f, 0.f, 0.f, 0.f};

    for (int it = 0; it < 16; it++) {
        int tap = z * 2 + (it >> 3);
        int ci0 = (it & 7) * 32;
        int kz = tap >> 4, ky = (tap >> 2) & 3, kx = tap & 3;
#pragma unroll
        for (int i = 0; i < 2; i++) {
            int u = tid + i * 256;
            int r = u >> 2, seg = (u & 3) * 8;
            uint4 av = make_uint4(0, 0, 0, 0);
            int p = m0 + r;
            if (p < NR) {
                int pz = p / 49, pr = p % 49, py = pr / 7, px = pr % 7;
                int n = (pz * 4 + kz) * 784 + (py * 4 + ky) * 28 + (px * 4 + kx);
                av = *(const uint4*)(xb + (size_t)n * 256 + ci0 + seg);
            }
            *(uint4*)(Asm + r * LDA + seg) = av;
            uint4 wv = *(const uint4*)(Wt + (size_t)tap * 65536 +
                                       (size_t)(n0 + r) * 256 + ci0 + seg);
            *(uint4*)(Bsm + r * LDA + seg) = wv;
        }
        __syncthreads();

        v8s af[4], bfr[4];
#pragma unroll
        for (int i = 0; i < 4; i++)
            af[i] = *(const v8s*)(Asm + (wm + i * 16 + fr) * LDA + fq * 8);
#pragma unroll
        for (int j = 0; j < 4; j++)
            bfr[j] = *(const v8s*)(Bsm + (wn + j * 16 + fr) * LDA + fq * 8);
#pragma unroll
        for (int i = 0; i < 4; i++)
#pragma unroll
            for (int j = 0; j < 4; j++)
                acc[i][j] = __builtin_amdgcn_mfma_f32_16x16x32_bf16(
                    af[i], bfr[j], acc[i][j], 0, 0, 0);
        __syncthreads();
    }

    float* dst = partials + (size_t)z * (NR * 256);
#pragma unroll
    for (int i = 0; i < 4; i++) {
#pragma unroll
        for (int j = 0; j < 4; j++) {
            int col = n0 + wn + j * 16 + fr;
#pragma unroll
            for (int r = 0; r < 4; r++) {
                int row = m0 + wm + i * 16 + fq * 4 + r;
                if (row < NR) dst[(size_t)row * 256 + col] = acc[i][j][r];
            }
        }
    }
}

// ---------------------------------------------------------------------------
// Reduce 32 partials + sr bias, LayerNorm (C=256) + exact GELU -> bf16.
// ---------------------------------------------------------------------------
__global__ __launch_bounds__(256) void ln_gelu_kernel(
    const float* __restrict__ partials, const float* __restrict__ srb,
    const float* __restrict__ g, const float* __restrict__ b,
    u16* __restrict__ out)
{
    int row = blockIdx.x, c = threadIdx.x;
    float v = srb[c];
#pragma unroll
    for (int s = 0; s < 32; s++)
        v += partials[(size_t)s * (NR * 256) + row * 256 + c];
    float s1 = v, s2 = v * v;
#pragma unroll
    for (int off = 1; off < 64; off <<= 1) {
        s1 += __shfl_xor(s1, off);
        s2 += __shfl_xor(s2, off);
    }
    __shared__ float ws[4], ws2[4];
    int wave = c >> 6, lane = c & 63;
    if (lane == 0) { ws[wave] = s1; ws2[wave] = s2; }
    __syncthreads();
    float mean = (ws[0] + ws[1] + ws[2] + ws[3]) * (1.f / 256.f);
    float m2   = (ws2[0] + ws2[1] + ws2[2] + ws2[3]) * (1.f / 256.f);
    float var  = m2 - mean * mean;
    float xn = (v - mean) * rsqrtf(var + 1e-5f) * g[c] + b[c];
    out[row * 256 + c] = f2bf(0.5f * xn * (1.f + erff(xn * 0.70710678118654752f)));
}

// ---------------------------------------------------------------------------
// Depthwise 3x3x3 SAME conv, LDS-tiled.  y = xall cols 0..255 (row stride 768).
// ---------------------------------------------------------------------------
__global__ __launch_bounds__(256) void dwconv_kernel(
    const u16* __restrict__ xall, const float* __restrict__ w,
    const float* __restrict__ bias, u16* __restrict__ out)
{
    __shared__ float sm[216 * 64];
    __shared__ float sw[64 * 27];
    const int tid = threadIdx.x;
    const int t  = blockIdx.x;
    const int g  = blockIdx.y;
    const int tz = t / 49, tr = t % 49, ty = tr / 7, tx = tr % 7;

    for (int u = tid; u < 64 * 27; u += 256) sw[u] = w[g * 64 * 27 + u];

    for (int u = tid; u < 216 * 8; u += 256) {
        int r = u >> 3, c8 = (u & 7) * 8;
        int vz = tz * 4 - 1 + r / 36;
        int rem = r % 36;
        int vy = ty * 4 - 1 + rem / 6;
        int vx = tx * 4 - 1 + rem % 6;
        float f[8];
        if ((unsigned)vz < 28u && (unsigned)vy < 28u && (unsigned)vx < 28u) {
            int n = vz * 784 + vy * 28 + vx;
            uint4 raw = *(const uint4*)(xall + (size_t)n * 768 + g * 64 + c8);
            f[0] = bf2f(raw.x & 0xffffu); f[1] = bf2f(raw.x >> 16);
            f[2] = bf2f(raw.y & 0xffffu); f[3] = bf2f(raw.y >> 16);
            f[4] = bf2f(raw.z & 0xffffu); f[5] = bf2f(raw.z >> 16);
            f[6] = bf2f(raw.w & 0xffffu); f[7] = bf2f(raw.w >> 16);
        } else {
#pragma unroll
            for (int i = 0; i < 8; i++) f[i] = 0.f;
        }
        float* dst = &sm[r * 64 + c8];
        *(float4*)dst       = make_float4(f[0], f[1], f[2], f[3]);
        *(float4*)(dst + 4) = make_float4(f[4], f[5], f[6], f[7]);
    }
    __syncthreads();

    const int c  = tid & 63;
    const int ch = g * 64 + c;
    float wreg[27];
#pragma unroll
    for (int j = 0; j < 27; j++) wreg[j] = sw[c * 27 + j];
    const float bc = bias[ch];

    const int vbase = (tid >> 6) * 16;
    for (int v = vbase; v < vbase + 16; v++) {
        int vz = v >> 4, vy = (v >> 2) & 3, vx = v & 3;
        float a = bc;
#pragma unroll
        for (int dz = 0; dz < 3; dz++)
#pragma unroll
            for (int dy = 0; dy < 3; dy++)
#pragma unroll
                for (int dx = 0; dx < 3; dx++)
                    a = fmaf(sm[((vz + dz) * 36 + (vy + dy) * 6 + (vx + dx)) * 64 + c],
                             wreg[dz * 9 + dy * 3 + dx], a);
        int n = (tz * 4 + vz) * 784 + (ty * 4 + vy) * 28 + (tx * 4 + vx);
        out[(size_t)n * 256 + ch] = f2bf(a);
    }
}

// ===========================================================================
// MFMA attention (round-6 validated).  Grid z splits the 22 m-tiles in half
// for 2 blocks/CU occupancy.
// ===========================================================================
#define KP  40    // K LDS row stride (bf16)
#define VTP 360   // V^T LDS row stride (bf16)
#define PP  40    // P LDS row stride (bf16)

// Branch 1: q = xall cols 256..383 (stride 768); kv1: [343,256].
__global__ __launch_bounds__(256) void attn1_kernel(
    const u16* __restrict__ xall, const u16* __restrict__ kv1,
    u16* __restrict__ o)
{
    __shared__ u16 Ks[352 * KP];
    __shared__ u16 VTs[32 * VTP];
    __shared__ u16 Ps[4 * 16 * PP];
    const int tid = threadIdx.x;
    const int h = blockIdx.y;
    const int qbase = blockIdx.x * 352;
    const int mt0 = blockIdx.z * 11;
    const int wave = tid >> 6, lane = tid & 63;
    const int fr = lane & 15, fq = lane >> 4;

    for (int u = tid; u < 352 * 4; u += 256) {
        int r = u >> 2, seg = u & 3;
        uint4 kq = make_uint4(0, 0, 0, 0), vq = make_uint4(0, 0, 0, 0);
        if (r < NR) {
            kq = *(const uint4*)(kv1 + (size_t)r * 256 + h * 32 + seg * 8);
            vq = *(const uint4*)(kv1 + (size_t)r * 256 + 128 + h * 32 + seg * 8);
        }
        *(uint4*)(Ks + r * KP + seg * 8) = kq;
        int d0 = seg * 8;
        VTs[(d0 + 0) * VTP + r] = (u16)(vq.x & 0xffffu);
        VTs[(d0 + 1) * VTP + r] = (u16)(vq.x >> 16);
        VTs[(d0 + 2) * VTP + r] = (u16)(vq.y & 0xffffu);
        VTs[(d0 + 3) * VTP + r] = (u16)(vq.y >> 16);
        VTs[(d0 + 4) * VTP + r] = (u16)(vq.z & 0xffffu);
        VTs[(d0 + 5) * VTP + r] = (u16)(vq.z >> 16);
        VTs[(d0 + 6) * VTP + r] = (u16)(vq.w & 0xffffu);
        VTs[(d0 + 7) * VTP + r] = (u16)(vq.w >> 16);
    }
    __syncthreads();

    u16* Pw = Ps + wave * 16 * PP;
    for (int mt = mt0 + wave; mt < mt0 + 11; mt += 4) {
        int qrow = qbase + mt * 16 + fr;
        v8s aq = {0, 0, 0, 0, 0, 0, 0, 0};
        if (qrow < N_TOK)
            aq = *(const v8s*)(xall + (size_t)qrow * 768 + 256 + h * 32 + fq * 8);

        v4f s[22];
#pragma unroll
        for (int t = 0; t < 22; t++) {
            v8s bk = *(const v8s*)(Ks + (t * 16 + fr) * KP + fq * 8);
            s[t] = __builtin_amdgcn_mfma_f32_16x16x32_bf16(
                aq, bk, (v4f){0.f, 0.f, 0.f, 0.f}, 0, 0, 0);
        }
        if (fr >= 7) {
#pragma unroll
            for (int r = 0; r < 4; r++) s[21][r] = -1e30f;
        }

        float inv_l[4];
#pragma unroll
        for (int r = 0; r < 4; r++) {
            float m = s[0][r];
#pragma unroll
            for (int t = 1; t < 22; t++) m = fmaxf(m, s[t][r]);
#pragma unroll
            for (int off = 1; off < 16; off <<= 1) m = fmaxf(m, __shfl_xor(m, off));
            float l = 0.f;
#pragma unroll
            for (int t = 0; t < 22; t++) {
                v4f sv = s[t];
                float p = __expf(sv[r] - m);
                sv[r] = p; s[t] = sv;
                l += p;
            }
#pragma unroll
            for (int off = 1; off < 16; off <<= 1) l += __shfl_xor(l, off);
            inv_l[r] = 1.f / l;
        }

        v4f o0 = {0.f, 0.f, 0.f, 0.f}, o1 = {0.f, 0.f, 0.f, 0.f};
#pragma unroll
        for (int kt = 0; kt < 11; kt++) {
#pragma unroll
            for (int tt = 0; tt < 2; tt++) {
                int t = kt * 2 + tt;
#pragma unroll
                for (int r = 0; r < 4; r++)
                    Pw[(fq * 4 + r) * PP + tt * 16 + fr] = f2bf(s[t][r]);
            }
            __asm__ volatile("s_waitcnt lgkmcnt(0)" ::: "memory");
            v8s ap  = *(const v8s*)(Pw + fr * PP + fq * 8);
            v8s bv0 = *(const v8s*)(VTs + fr * VTP + kt * 32 + fq * 8);
            v8s bv1 = *(const v8s*)(VTs + (16 + fr) * VTP + kt * 32 + fq * 8);
            o0 = __builtin_amdgcn_mfma_f32_16x16x32_bf16(ap, bv0, o0, 0, 0, 0);
            o1 = __builtin_amdgcn_mfma_f32_16x16x32_bf16(ap, bv1, o1, 0, 0, 0);
        }

#pragma unroll
        for (int r = 0; r < 4; r++) {
            int n = qbase + mt * 16 + fq * 4 + r;
            if (n < N_TOK) {
                u16* op = o + (size_t)n * 256 + h * 32;
                op[fr]      = f2bf(o0[r] * inv_l[r]);
                op[16 + fr] = f2bf(o1[r] * inv_l[r]);
            }
        }
    }
}

// Branch 2: q = xall cols 384..511; kv2 = xall cols 512..767 (stride 768).
__global__ __launch_bounds__(256) void attn2_kernel(
    const u16* __restrict__ xall, u16* __restrict__ o)
{
    __shared__ u16 Ks[352 * KP];
    __shared__ u16 VTs[32 * VTP];
    __shared__ u16 Ps[4 * 16 * PP];
    const int tid = threadIdx.x;
    const int h  = blockIdx.y;
    const int wi = blockIdx.x;
    const int zb = (wi >> 4) & 3, yb = (wi >> 2) & 3, xb = wi & 3;
    const int mt0 = blockIdx.z * 11;
    const int wave = tid >> 6, lane = tid & 63;
    const int fr = lane & 15, fq = lane >> 4;

    for (int u = tid; u < 352 * 4; u += 256) {
        int r = u >> 2, seg = u & 3;
        uint4 kq = make_uint4(0, 0, 0, 0), vq = make_uint4(0, 0, 0, 0);
        if (r < NR) {
            int mz = r / 49, mr = r % 49, my = mr / 7, mx = mr % 7;
            int nk = (zb * 7 + mz) * 784 + (yb * 7 + my) * 28 + (xb * 7 + mx);
            const u16* base = xall + (size_t)nk * 768 + 512;
            kq = *(const uint4*)(base + h * 32 + seg * 8);
            vq = *(const uint4*)(base + 128 + h * 32 + seg * 8);
        }
        *(uint4*)(Ks + r * KP + seg * 8) = kq;
        int d0 = seg * 8;
        VTs[(d0 + 0) * VTP + r] = (u16)(vq.x & 0xffffu);
        VTs[(d0 + 1) * VTP + r] = (u16)(vq.x >> 16);
        VTs[(d0 + 2) * VTP + r] = (u16)(vq.y & 0xffffu);
        VTs[(d0 + 3) * VTP + r] = (u16)(vq.y >> 16);
        VTs[(d0 + 4) * VTP + r] = (u16)(vq.z & 0xffffu);
        VTs[(d0 + 5) * VTP + r] = (u16)(vq.z >> 16);
        VTs[(d0 + 6) * VTP + r] = (u16)(vq.w & 0xffffu);
        VTs[(d0 + 7) * VTP + r] = (u16)(vq.w >> 16);
    }
    __syncthreads();

    u16* Pw = Ps + wave * 16 * PP;
    for (int mt = mt0 + wave; mt < mt0 + 11; mt += 4) {
        int tw = mt * 16 + fr;
        v8s aq = {0, 0, 0, 0, 0, 0, 0, 0};
        if (tw < NR) {
            int wz = tw / 49, tr2 = tw % 49, wy = tr2 / 7, wx = tr2 % 7;
            int nq = (zb * 7 + wz) * 784 + (yb * 7 + wy) * 28 + (xb * 7 + wx);
            aq = *(const v8s*)(xall + (size_t)nq * 768 + 384 + h * 32 + fq * 8);
        }

        v4f s[22];
#pragma unroll
        for (int t = 0; t < 22; t++) {
            v8s bk = *(const v8s*)(Ks + (t * 16 + fr) * KP + fq * 8);
            s[t] = __builtin_amdgcn_mfma_f32_16x16x32_bf16(
                aq, bk, (v4f){0.f, 0.f, 0.f, 0.f}, 0, 0, 0);
        }
        if (fr >= 7) {
#pragma unroll
            for (int r = 0; r < 4; r++) s[21][r] = -1e30f;
        }

        float inv_l[4];
#pragma unroll
        for (int r = 0; r < 4; r++) {
            float m = s[0][r];
#pragma unroll
            for (int t = 1; t < 22; t++) m = fmaxf(m, s[t][r]);
#pragma unroll
            for (int off = 1; off < 16; off <<= 1) m = fmaxf(m, __shfl_xor(m, off));
            float l = 0.f;
#pragma unroll
            for (int t = 0; t < 22; t++) {
                v4f sv = s[t];
                float p = __expf(sv[r] - m);
                sv[r] = p; s[t] = sv;
                l += p;
            }
#pragma unroll
            for (int off = 1; off < 16; off <<= 1) l += __shfl_xor(l, off);
            inv_l[r] = 1.f / l;
        }

        v4f o0 = {0.f, 0.f, 0.f, 0.f}, o1 = {0.f, 0.f, 0.f, 0.f};
#pragma unroll
        for (int kt = 0; kt < 11; kt++) {
#pragma unroll
            for (int tt = 0; tt < 2; tt++) {
                int t = kt * 2 + tt;
#pragma unroll
                for (int r = 0; r < 4; r++)
                    Pw[(fq * 4 + r) * PP + tt * 16 + fr] = f2bf(s[t][r]);
            }
            __asm__ volatile("s_waitcnt lgkmcnt(0)" ::: "memory");
            v8s ap  = *(const v8s*)(Pw + fr * PP + fq * 8);
            v8s bv0 = *(const v8s*)(VTs + fr * VTP + kt * 32 + fq * 8);
            v8s bv1 = *(const v8s*)(VTs + (16 + fr) * VTP + kt * 32 + fq * 8);
            o0 = __builtin_amdgcn_mfma_f32_16x16x32_bf16(ap, bv0, o0, 0, 0, 0);
            o1 = __builtin_amdgcn_mfma_f32_16x16x32_bf16(ap, bv1, o1, 0, 0, 0);
        }

#pragma unroll
        for (int r = 0; r < 4; r++) {
            int ts = mt * 16 + fq * 4 + r;
            if (ts < NR) {
                int wz = ts / 49, tr2 = ts % 49, wy = tr2 / 7, wx = tr2 % 7;
                int nq = (zb * 7 + wz) * 784 + (yb * 7 + wy) * 28 + (xb * 7 + wx);
                u16* op = o + (size_t)nq * 256 + 128 + h * 32;
                op[fr]      = f2bf(o0[r] * inv_l[r]);
                op[16 + fr] = f2bf(o1[r] * inv_l[r]);
            }
        }
    }
}

// ---------------------------------------------------------------------------
extern "C" void kernel_launch(void* const* d_in, const int* in_sizes, int n_in,
                              void* d_out, int out_size, void* d_ws, size_t ws_size,
                              hipStream_t stream)
{
    const float* x       = (const float*)d_in[0];
    const float* lepe_w  = (const float*)d_in[4];
    const float* lepe_b  = (const float*)d_in[5];
    const float* lconv_w = (const float*)d_in[6];
    const float* lconv_b = (const float*)d_in[7];
    const float* sr_w    = (const float*)d_in[8];
    const float* sr_b    = (const float*)d_in[9];
    const float* norm_g  = (const float*)d_in[10];
    const float* norm_b  = (const float*)d_in[11];
    const float* q1_w    = (const float*)d_in[12];
    const float* kv1_w   = (const float*)d_in[13];
    const float* q2_w    = (const float*)d_in[14];
    const float* kv2_w   = (const float*)d_in[15];
    const float* proj_w  = (const float*)d_in[16];
    const float* proj_b  = (const float*)d_in[17];
    float* out = (float*)d_out;

    const size_t NC = (size_t)N_TOK * 256;

    float* partials = (float*)d_ws;                 // [32][343*256] fp32
    float* bias_all = partials + 32 * (NR * 256);   // [768]
    u16* xb     = (u16*)(bias_all + 768);           // bf16(x) [N,256]
    u16* xall   = xb + NC;                          // [N,768]: y|q1|q2|kv2
    u16* lepeb  = xall + (size_t)N_TOK * 768;       // [N,256]
    u16* colb   = lepeb + NC;                       // o concat [N,256]
    u16* x1b    = colb + NC;                        // [343,256]
    u16* kv1b   = x1b + NR * 256;                   // [343,256]
    u16* wb_comb = kv1b + NR * 256;                 // [768,256]
    u16* wb_k1  = wb_comb + 196608;                 // [256,256]
    u16* wb_p   = wb_k1 + 65536;                    // [256,256]
    u16* wsr_t  = wb_p + 65536;                     // [64][256,256]
    size_t need = (size_t)(32 * NR * 256 + 768) * 4 +
                  (NC + (size_t)N_TOK * 768 + 3 * NC + 2 * (size_t)NR * 256 +
                   196608 + 2 * 65536 + 4194304) * 2;
    if (ws_size < need) return;

    // 0a. weights -> bf16 (q pre-scaled), bias_all
    convert_w_kernel<<<dim3(321), 256, 0, stream>>>(
        lepe_w, q1_w, q2_w, kv2_w, kv1_w, proj_w, lepe_b,
        wb_comb, wb_k1, wb_p, bias_all);
    // 0b. sr_w -> [tap][co][ci] bf16
    convert_sr_kernel<<<dim3(256), 256, 0, stream>>>(sr_w, wsr_t);
    // 0c. x -> bf16
    convert_x_kernel<<<dim3(2744), 256, 0, stream>>>(x, xb);
    // 1. xall = xb @ [lepe|q1|q2|kv2]^T + bias_all   (bf16 A path, bf16 out)
    gemm_bf16<<<dim3(172, 6), 256, 0, stream>>>(xb, nullptr, wb_comb, bias_all,
                                                xall, N_TOK, 256, 768, 0, 0);
    // 2. lepe = depthwise conv(y)
    dwconv_kernel<<<dim3(343, 4), 256, 0, stream>>>(xall, lconv_w, lconv_b, lepeb);
    // 3. SR conv: tap-split GEMM into partials (A staged from xb)
    sr_gemm<<<dim3(3, 2, 32), 256, 0, stream>>>(xb, wsr_t, partials);
    // 4. x1 = gelu(layernorm(sum partials + sr_b))
    ln_gelu_kernel<<<dim3(NR), 256, 0, stream>>>(partials, sr_b, norm_g, norm_b, x1b);
    // 5. kv1 = x1 @ kv1_w^T
    gemm_bf16<<<dim3(3, 2), 256, 0, stream>>>(x1b, nullptr, wb_k1, nullptr,
                                              kv1b, NR, 256, 256, 0, 0);
    // 6. branch-1 MFMA attention -> o[:, :128]
    attn1_kernel<<<dim3(63, 4, 2), 256, 0, stream>>>(xall, kv1b, colb);
    // 7. branch-2 windowed MFMA attention -> o[:, 128:]
    attn2_kernel<<<dim3(64, 4, 2), 256, 0, stream>>>(xall, colb);
    // 8. out = (o + lepe) @ proj_w^T + proj_b  (fp32 out)
    gemm_bf16<<<dim3(172, 2), 256, 0, stream>>>(colb, lepeb, wb_p, proj_b,
                                                out, N_TOK, 256, 256, 0, 1);
}